// Round 1
// baseline (899.680 us; speedup 1.0000x reference)
//
#include <hip/hip_runtime.h>
#include <stdint.h>
#include <math.h>

#define N_PTS 4096
#define DIM   512
#define KM1   7
#define NDRAW (N_PTS * KM1)     // 28672
#define MASKW (N_PTS / 32)      // 128 words per row

// ---------------- threefry2x32, key = (0, 42), JAX partitionable bits ----------------
__device__ __forceinline__ uint32_t rotl32(uint32_t x, uint32_t r) {
  return (x << r) | (x >> (32u - r));
}

__device__ __forceinline__ uint32_t threefry_bits(uint32_t x0, uint32_t x1) {
  const uint32_t ks0 = 0u, ks1 = 42u, ks2 = (0u ^ 42u ^ 0x1BD11BDAu);
  x0 += ks0; x1 += ks1;
#define TFR(r) { x0 += x1; x1 = rotl32(x1, r); x1 ^= x0; }
  TFR(13u) TFR(15u) TFR(26u) TFR(6u)   x0 += ks1; x1 += ks2 + 1u;
  TFR(17u) TFR(29u) TFR(16u) TFR(24u)  x0 += ks2; x1 += ks0 + 2u;
  TFR(13u) TFR(15u) TFR(26u) TFR(6u)   x0 += ks0; x1 += ks1 + 3u;
  TFR(17u) TFR(29u) TFR(16u) TFR(24u)  x0 += ks1; x1 += ks2 + 4u;
  TFR(13u) TFR(15u) TFR(26u) TFR(6u)   x0 += ks2; x1 += ks0 + 5u;
#undef TFR
  return x0 ^ x1;   // partitionable 32-bit: out0 ^ out1
}

// u = max(tiny, bitcast(bits>>9 | 1.0f) - 1);  g = -log(-log(u))   (all f32, mirrors XLA)
__device__ __forceinline__ float gumbel_from_bits(uint32_t bits) {
  float f = __uint_as_float((bits >> 9) | 0x3f800000u) - 1.0f;
  float u = fmaxf(f, 1.17549435e-38f);
  float a = logf(u);
  float b = logf(-a);
  return -b;
}

// ---------------- kernel 0: sq[i] = f32(sum_k x[i,k]^2) (f64 accumulate) ----------------
__global__ __launch_bounds__(64) void sq_kernel(const float* __restrict__ x,
                                                float* __restrict__ sq) {
  const int i = blockIdx.x;
  const int t = threadIdx.x;
  const float* row = x + (size_t)i * DIM;
  double s = 0.0;
  for (int k = t; k < DIM; k += 64) { double v = (double)row[k]; s += v * v; }
  for (int off = 32; off > 0; off >>= 1) s += __shfl_down(s, off, 64);
  if (t == 0) sq[i] = (float)s;
}

// ---------------- kernel 1: validity bitmask via f64-accumulated Gram matrix ----------------
#define TILE 64
#define BKK  16

__global__ __launch_bounds__(256) void valid_kernel(const float* __restrict__ x,
                                                    const float* __restrict__ sq,
                                                    uint32_t* __restrict__ mask) {
  __shared__ double As[BKK][TILE];
  __shared__ double Bs[BKK][TILE];
  __shared__ uint32_t smask[TILE][2];

  const int i0 = blockIdx.y * TILE;
  const int c0 = blockIdx.x * TILE;
  const int t  = threadIdx.x;
  const int tx = t & 15;    // 16 col-groups of 4
  const int ty = t >> 4;    // 16 row-groups of 4
  const int lrow = t >> 2;  // staging: row 0..63
  const int lseg = t & 3;   // staging: 4-float k-segment

  double acc[4][4];
#pragma unroll
  for (int r = 0; r < 4; ++r)
#pragma unroll
    for (int c = 0; c < 4; ++c) acc[r][c] = 0.0;

  const float* aptr = x + (size_t)(i0 + lrow) * DIM + lseg * 4;
  const float* bptr = x + (size_t)(c0 + lrow) * DIM + lseg * 4;

  for (int k0 = 0; k0 < DIM; k0 += BKK) {
    float4 av = *(const float4*)(aptr + k0);
    float4 bv = *(const float4*)(bptr + k0);
    __syncthreads();
    As[lseg * 4 + 0][lrow] = (double)av.x;
    As[lseg * 4 + 1][lrow] = (double)av.y;
    As[lseg * 4 + 2][lrow] = (double)av.z;
    As[lseg * 4 + 3][lrow] = (double)av.w;
    Bs[lseg * 4 + 0][lrow] = (double)bv.x;
    Bs[lseg * 4 + 1][lrow] = (double)bv.y;
    Bs[lseg * 4 + 2][lrow] = (double)bv.z;
    Bs[lseg * 4 + 3][lrow] = (double)bv.w;
    __syncthreads();
#pragma unroll
    for (int k = 0; k < BKK; ++k) {
      double a0 = As[k][ty * 4 + 0], a1 = As[k][ty * 4 + 1];
      double a2 = As[k][ty * 4 + 2], a3 = As[k][ty * 4 + 3];
      double b0 = Bs[k][tx * 4 + 0], b1 = Bs[k][tx * 4 + 1];
      double b2 = Bs[k][tx * 4 + 2], b3 = Bs[k][tx * 4 + 3];
      acc[0][0] = fma(a0, b0, acc[0][0]); acc[0][1] = fma(a0, b1, acc[0][1]);
      acc[0][2] = fma(a0, b2, acc[0][2]); acc[0][3] = fma(a0, b3, acc[0][3]);
      acc[1][0] = fma(a1, b0, acc[1][0]); acc[1][1] = fma(a1, b1, acc[1][1]);
      acc[1][2] = fma(a1, b2, acc[1][2]); acc[1][3] = fma(a1, b3, acc[1][3]);
      acc[2][0] = fma(a2, b0, acc[2][0]); acc[2][1] = fma(a2, b1, acc[2][1]);
      acc[2][2] = fma(a2, b2, acc[2][2]); acc[2][3] = fma(a2, b3, acc[2][3]);
      acc[3][0] = fma(a3, b0, acc[3][0]); acc[3][1] = fma(a3, b1, acc[3][1]);
      acc[3][2] = fma(a3, b2, acc[3][2]); acc[3][3] = fma(a3, b3, acc[3][3]);
    }
  }

  if (t < TILE * 2) smask[t >> 1][t & 1] = 0u;
  __syncthreads();

#pragma unroll
  for (int r = 0; r < 4; ++r) {
    const int gi = i0 + ty * 4 + r;
    const float sqi = sq[gi];
    uint32_t bits = 0u;
#pragma unroll
    for (int c = 0; c < 4; ++c) {
      const int gc = c0 + tx * 4 + c;
      // mirror reference f32 ops: dist2 = (sq_i + sq_c) - 2*dot; d = sqrt(dist2); d < 1.4
      float dot32 = (float)acc[r][c];
      float tsum  = sqi + sq[gc];
      float dist2 = tsum - 2.0f * dot32;
      float d = sqrtf(dist2);
      bool v = (d < 1.4f) && ((gi >> 3) != (gc >> 3));   // different batch_k block
      bits |= v ? (1u << ((tx * 4 + c) & 31)) : 0u;
    }
    atomicOr(&smask[ty * 4 + r][tx >> 3], bits);
  }
  __syncthreads();
  if (t < TILE * 2) {
    const int row = t >> 1, w = t & 1;
    mask[(size_t)(i0 + row) * MASKW + (c0 >> 5) + w] = smask[row][w];
  }
}

// ---------------- kernel 2: per-(j,i) draw = argmax over valid c of (gumbel + L) ----------------
__global__ __launch_bounds__(256) void sample_kernel(const uint32_t* __restrict__ mask,
                                                     int* __restrict__ nidx) {
  const int r = blockIdx.x;          // r = j*4096 + i, 0..28671
  const int j = r >> 12;
  const int i = r & (N_PTS - 1);
  const int t = threadIdx.x;

  __shared__ uint32_t m[MASKW];
  __shared__ float sval[256];
  __shared__ int   sidx[256];

  if (t < MASKW) m[t] = mask[(size_t)i * MASKW + t];
  __syncthreads();

  int n = 0;
#pragma unroll
  for (int w = 0; w < MASKW; ++w) n += __popc(m[w]);
  const bool fallback = (n == 0);     // ref: rows with no valid negatives -> uniform over all
  float L = 0.0f;
  if (!fallback) {
    float rowsum = (float)((double)n * (double)0.01f);   // ~= ref's f32 sum of n copies of 0.01f
    L = logf(0.01f / (1e-4f + rowsum));                  // logit, constant per row
  }

  float best = -__builtin_inff();
  int bi = 0x7fffffff;
  const uint32_t base = ((uint32_t)r << 12);             // idx = r*4096 + c
  for (int c = t; c < N_PTS; c += 256) {
    bool valid = fallback || ((m[c >> 5] >> (c & 31)) & 1u);
    if (!valid) continue;
    uint32_t bits = threefry_bits(0u, base + (uint32_t)c);
    float v = gumbel_from_bits(bits) + L;
    if (v > best) { best = v; bi = c; }                  // strict > keeps lowest c per thread
  }
  sval[t] = best; sidx[t] = bi;
  __syncthreads();
  for (int s = 128; s > 0; s >>= 1) {
    if (t < s) {
      float v2 = sval[t + s]; int i2 = sidx[t + s];
      if (v2 > sval[t] || (v2 == sval[t] && i2 < sidx[t])) { sval[t] = v2; sidx[t] = i2; }
    }
    __syncthreads();
  }
  if (t == 0) nidx[i * KM1 + j] = sidx[0];
}

// ---------------- kernel 3: assemble (a_idx, x[a], x[p], x[n], x) into d_out ----------------
__global__ __launch_bounds__(256) void assemble_kernel(const float* __restrict__ x,
                                                       const int* __restrict__ nidx,
                                                       float* __restrict__ out) {
  const int B1 = 7168;                 // a_idx: 28672 floats = 7168 float4
  const int SEC = NDRAW * (DIM / 4);   // 3,670,016 float4 per gathered section
  const int B2 = B1 + SEC;
  const int B3 = B2 + SEC;
  const int B4 = B3 + SEC;
  const int TOT = B4 + N_PTS * (DIM / 4);   // 11,541,504 float4 total

  const float4* x4 = (const float4*)x;
  float4* o4 = (float4*)out;

  for (int q = blockIdx.x * blockDim.x + threadIdx.x; q < TOT;
       q += gridDim.x * blockDim.x) {
    float4 v;
    if (q < B1) {
      int e = q * 4;
      v.x = (float)((e + 0) / KM1);
      v.y = (float)((e + 1) / KM1);
      v.z = (float)((e + 2) / KM1);
      v.w = (float)((e + 3) / KM1);
    } else {
      int src, rem;
      if (q < B2) {
        rem = q - B1; int tt = rem >> 7; src = tt / KM1;                     // x[a_idx]
      } else if (q < B3) {
        rem = q - B2; int tt = rem >> 7; int i = tt / KM1; int mm = tt - i * KM1;
        int s = i & 7; int bs = i & ~7;
        src = bs + mm + (mm >= s ? 1 : 0);                                   // x[p_idx]
      } else if (q < B4) {
        rem = q - B3; int tt = rem >> 7; src = nidx[tt];                     // x[n_idx]
      } else {
        rem = q - B4; src = rem >> 7;                                        // x
      }
      int col = rem & 127;
      v = x4[(size_t)src * (DIM / 4) + col];
    }
    o4[q] = v;
  }
}

// ---------------- launch ----------------
extern "C" void kernel_launch(void* const* d_in, const int* in_sizes, int n_in,
                              void* d_out, int out_size, void* d_ws, size_t ws_size,
                              hipStream_t stream) {
  const float* x = (const float*)d_in[0];
  float* out = (float*)d_out;

  uint8_t* ws = (uint8_t*)d_ws;
  uint32_t* mask = (uint32_t*)ws;                                    // 2 MiB
  int* nidx = (int*)(ws + (size_t)N_PTS * MASKW * 4);                // 112 KiB
  float* sq = (float*)(ws + (size_t)N_PTS * MASKW * 4 + (size_t)NDRAW * 4);  // 16 KiB

  sq_kernel<<<N_PTS, 64, 0, stream>>>(x, sq);
  dim3 g1(N_PTS / TILE, N_PTS / TILE);
  valid_kernel<<<g1, 256, 0, stream>>>(x, sq, mask);
  sample_kernel<<<NDRAW, 256, 0, stream>>>(mask, nidx);
  assemble_kernel<<<2048, 256, 0, stream>>>(x, nidx, out);
}

// Round 2
// 576.583 us; speedup vs baseline: 1.5604x; 1.5604x over previous
//
#include <hip/hip_runtime.h>
#include <stdint.h>
#include <math.h>

#define N_PTS 4096
#define DIM   512
#define KM1   7
#define NDRAW (N_PTS * KM1)     // 28672
#define MASKW (N_PTS / 32)      // 128 words per row
#define NP    ((size_t)N_PTS * DIM)

typedef __attribute__((ext_vector_type(8))) short bf16x8;
typedef __attribute__((ext_vector_type(4))) float f32x4;

// ---------------- threefry2x32, key = (0, 42), JAX partitionable bits ----------------
__device__ __forceinline__ uint32_t rotl32(uint32_t x, uint32_t r) {
  return (x << r) | (x >> (32u - r));
}

__device__ __forceinline__ uint32_t threefry_bits(uint32_t x0, uint32_t x1) {
  const uint32_t ks0 = 0u, ks1 = 42u, ks2 = (0u ^ 42u ^ 0x1BD11BDAu);
  x0 += ks0; x1 += ks1;
#define TFR(r) { x0 += x1; x1 = rotl32(x1, r); x1 ^= x0; }
  TFR(13u) TFR(15u) TFR(26u) TFR(6u)   x0 += ks1; x1 += ks2 + 1u;
  TFR(17u) TFR(29u) TFR(16u) TFR(24u)  x0 += ks2; x1 += ks0 + 2u;
  TFR(13u) TFR(15u) TFR(26u) TFR(6u)   x0 += ks0; x1 += ks1 + 3u;
  TFR(17u) TFR(29u) TFR(16u) TFR(24u)  x0 += ks1; x1 += ks2 + 4u;
  TFR(13u) TFR(15u) TFR(26u) TFR(6u)   x0 += ks2; x1 += ks0 + 5u;
#undef TFR
  return x0 ^ x1;   // partitionable 32-bit: out0 ^ out1
}

__device__ __forceinline__ float gumbel_from_bits(uint32_t bits) {
  float f = __uint_as_float((bits >> 9) | 0x3f800000u) - 1.0f;
  float u = fmaxf(f, 1.17549435e-38f);
  float a = logf(u);
  float b = logf(-a);
  return -b;
}

__device__ __forceinline__ ushort bf16rn(float f) {
  uint32_t u = __float_as_uint(f);
  uint32_t r = (u + 0x7FFFu + ((u >> 16) & 1u)) >> 16;
  return (ushort)r;
}

// ---------------- kernel A: split x into 3 bf16 planes (hi, mid, lo) ----------------
__global__ __launch_bounds__(256) void split_kernel(const float* __restrict__ x,
                                                    ushort* __restrict__ xs) {
  const int q = blockIdx.x * 256 + threadIdx.x;   // 0..524287, 4 floats each
  float4 v = ((const float4*)x)[q];
  float a[4] = {v.x, v.y, v.z, v.w};
  ushort4 oh, om, ol;
  ushort hh[4], mm[4], ll[4];
#pragma unroll
  for (int j = 0; j < 4; ++j) {
    float f = a[j];
    ushort hb = bf16rn(f);
    float hf = __uint_as_float(((uint32_t)hb) << 16);
    float r1 = f - hf;                 // exact in f32
    ushort mb = bf16rn(r1);
    float mf = __uint_as_float(((uint32_t)mb) << 16);
    float r2 = r1 - mf;                // exact in f32
    ushort lb = bf16rn(r2);
    hh[j] = hb; mm[j] = mb; ll[j] = lb;
  }
  oh.x = hh[0]; oh.y = hh[1]; oh.z = hh[2]; oh.w = hh[3];
  om.x = mm[0]; om.y = mm[1]; om.z = mm[2]; om.w = mm[3];
  ol.x = ll[0]; ol.y = ll[1]; ol.z = ll[2]; ol.w = ll[3];
  ((ushort4*)xs)[q]            = oh;
  ((ushort4*)(xs + NP))[q]     = om;
  ((ushort4*)(xs + 2 * NP))[q] = ol;
}

// ---------------- kernel 0: sq[i] = f32(sum_k x[i,k]^2) (f64 accumulate) ----------------
__global__ __launch_bounds__(64) void sq_kernel(const float* __restrict__ x,
                                                float* __restrict__ sq) {
  const int i = blockIdx.x;
  const int t = threadIdx.x;
  const float* row = x + (size_t)i * DIM;
  double s = 0.0;
  for (int k = t; k < DIM; k += 64) { double v = (double)row[k]; s += v * v; }
  for (int off = 32; off > 0; off >>= 1) s += __shfl_down(s, off, 64);
  if (t == 0) sq[i] = (float)s;
}

// ---------------- kernel 1: validity bitmask via split-bf16 MFMA Gram ----------------
#define BM 128
#define BK 32

__device__ __forceinline__ void gload_lds16(const ushort* g, ushort* l) {
#if __has_builtin(__builtin_amdgcn_global_load_lds)
  __builtin_amdgcn_global_load_lds((__attribute__((address_space(1))) void*)(ushort*)g,
                                   (__attribute__((address_space(3))) void*)l, 16, 0, 0);
#else
  // fallback handled in kernel body (never taken on gfx950/ROCm>=7)
#endif
}

__global__ __launch_bounds__(256) void gram_kernel(const ushort* __restrict__ xs,
                                                   const float* __restrict__ sq,
                                                   uint32_t* __restrict__ mask) {
  __shared__ __align__(1024) ushort As[BM * BK];   // 8 KB, linear [row][k], 64B rows
  __shared__ __align__(1024) ushort Bs[BM * BK];   // 8 KB
  __shared__ uint32_t smask[BM][4];                // 2 KB validity bits for this 128x128 tile

  const int tid = threadIdx.x;
  const int w = tid >> 6, l = tid & 63;
  const int i0 = blockIdx.y * BM, c0 = blockIdx.x * BM;
  const int wr = w >> 1, wc = w & 1;               // wave's 64x64 subtile

  // init smask
  ((uint32_t*)smask)[tid] = 0u;
  ((uint32_t*)smask)[tid + 256] = 0u;

  f32x4 acc[4][4] = {};

  // staging geometry: per 8KB tile, wave w handles 2 chunks of 1024B
  const int d0 = (w * 2) * 1024 + l * 16;          // dest byte of lane (chunk 0)
  const int d1 = d0 + 1024;                        // chunk 1
  const int r0 = d0 >> 6, e0 = (d0 & 63) >> 1;     // source row / element within tile
  const int r1 = d1 >> 6, e1 = (d1 & 63) >> 1;

  // frag read offsets (constant across k-steps)
  const int aoff = (wr * 64 + (l & 15)) * BK + (l >> 4) * 8;
  const int boff = (wc * 64 + (l & 15)) * BK + (l >> 4) * 8;

  const int PA[6] = {0, 0, 1, 0, 2, 1};
  const int PB[6] = {0, 1, 0, 2, 0, 1};

  for (int pair = 0; pair < 6; ++pair) {
    const ushort* pa = xs + (size_t)PA[pair] * NP + (size_t)i0 * DIM;
    const ushort* pb = xs + (size_t)PB[pair] * NP + (size_t)c0 * DIM;
    const ushort* ga0 = pa + (size_t)r0 * DIM + e0;
    const ushort* ga1 = pa + (size_t)r1 * DIM + e1;
    const ushort* gb0 = pb + (size_t)r0 * DIM + e0;
    const ushort* gb1 = pb + (size_t)r1 * DIM + e1;
#pragma unroll 4
    for (int ks = 0; ks < DIM / BK; ++ks) {
      const int k0 = ks * BK;
      __syncthreads();                              // prev compute done
      gload_lds16(ga0 + k0, &As[(w * 2 + 0) * 512]);
      gload_lds16(ga1 + k0, &As[(w * 2 + 1) * 512]);
      gload_lds16(gb0 + k0, &Bs[(w * 2 + 0) * 512]);
      gload_lds16(gb1 + k0, &Bs[(w * 2 + 1) * 512]);
      __syncthreads();                              // vmcnt(0) drain: tile ready
      bf16x8 af[4], bf[4];
#pragma unroll
      for (int m = 0; m < 4; ++m) af[m] = *(const bf16x8*)(&As[aoff + m * 16 * BK]);
#pragma unroll
      for (int n = 0; n < 4; ++n) bf[n] = *(const bf16x8*)(&Bs[boff + n * 16 * BK]);
#pragma unroll
      for (int m = 0; m < 4; ++m)
#pragma unroll
        for (int n = 0; n < 4; ++n)
          acc[m][n] = __builtin_amdgcn_mfma_f32_16x16x32_bf16(af[m], bf[n], acc[m][n], 0, 0, 0);
    }
  }

  __syncthreads();

  // epilogue: dist2 -> validity bits (mirror reference f32 op order)
#pragma unroll
  for (int m = 0; m < 4; ++m) {
    const int gi_base = i0 + wr * 64 + m * 16;
#pragma unroll
    for (int n = 0; n < 4; ++n) {
      const int gc = c0 + wc * 64 + n * 16 + (l & 15);
      const float sqc = sq[gc];
#pragma unroll
      for (int reg = 0; reg < 4; ++reg) {
        const int gi = gi_base + (l >> 4) * 4 + reg;
        float dot = acc[m][n][reg];
        float tsum = sq[gi] + sqc;
        float dist2 = tsum - 2.0f * dot;
        float d = sqrtf(dist2);
        bool v = (d < 1.4f) && ((gi >> 3) != (gc >> 3));
        unsigned long long b = __ballot(v);
        if (l < 4) {     // lane g' extracts 16 cols for row m*16+4g'+reg
          uint32_t chunk = (uint32_t)((b >> (16 * l)) & 0xFFFFull);
          int rowL = wr * 64 + m * 16 + 4 * l + reg;
          atomicOr(&smask[rowL][wc * 2 + (n >> 1)], chunk << (16 * (n & 1)));
        }
      }
    }
  }
  __syncthreads();
  for (int t = tid; t < 512; t += 256) {
    int row = t >> 2, wrd = t & 3;
    mask[(size_t)(i0 + row) * MASKW + (c0 >> 5) + wrd] = smask[row][wrd];
  }
}

// ---------------- kernel 2: per-(j,i) draw = argmax over valid c of gumbel ----------------
__global__ __launch_bounds__(256) void sample_kernel(const uint32_t* __restrict__ mask,
                                                     int* __restrict__ nidx) {
  const int r = blockIdx.x;          // r = j*4096 + i
  const int j = r >> 12;
  const int i = r & (N_PTS - 1);
  const int t = threadIdx.x;

  __shared__ uint32_t m[MASKW];
  __shared__ float sval[256];
  __shared__ int   sidx[256];

  if (t < MASKW) m[t] = mask[(size_t)i * MASKW + t];
  __syncthreads();

  int n = 0;
#pragma unroll
  for (int w = 0; w < MASKW; ++w) n += __popc(m[w]);
  const bool fallback = (n == 0);
  float L = 0.0f;
  if (!fallback) {
    float rowsum = (float)((double)n * (double)0.01f);
    L = logf(0.01f / (1e-4f + rowsum));
  }

  float best = -__builtin_inff();
  int bi = 0x7fffffff;
  const uint32_t base = ((uint32_t)r << 12);
  for (int c = t; c < N_PTS; c += 256) {
    bool valid = fallback || ((m[c >> 5] >> (c & 31)) & 1u);
    if (!valid) continue;
    uint32_t bits = threefry_bits(0u, base + (uint32_t)c);
    float v = gumbel_from_bits(bits) + L;
    if (v > best) { best = v; bi = c; }
  }
  sval[t] = best; sidx[t] = bi;
  __syncthreads();
  for (int s = 128; s > 0; s >>= 1) {
    if (t < s) {
      float v2 = sval[t + s]; int i2 = sidx[t + s];
      if (v2 > sval[t] || (v2 == sval[t] && i2 < sidx[t])) { sval[t] = v2; sidx[t] = i2; }
    }
    __syncthreads();
  }
  if (t == 0) nidx[i * KM1 + j] = sidx[0];
}

// ---------------- kernel 3: assemble (a_idx, x[a], x[p], x[n], x) ----------------
__global__ __launch_bounds__(256) void assemble_kernel(const float* __restrict__ x,
                                                       const int* __restrict__ nidx,
                                                       float* __restrict__ out) {
  const int B1 = 7168;
  const int SEC = NDRAW * (DIM / 4);
  const int B2 = B1 + SEC;
  const int B3 = B2 + SEC;
  const int B4 = B3 + SEC;
  const int TOT = B4 + N_PTS * (DIM / 4);

  const float4* x4 = (const float4*)x;
  float4* o4 = (float4*)out;

  for (int q = blockIdx.x * blockDim.x + threadIdx.x; q < TOT;
       q += gridDim.x * blockDim.x) {
    float4 v;
    if (q < B1) {
      int e = q * 4;
      v.x = (float)((e + 0) / KM1);
      v.y = (float)((e + 1) / KM1);
      v.z = (float)((e + 2) / KM1);
      v.w = (float)((e + 3) / KM1);
    } else {
      int src, rem;
      if (q < B2) {
        rem = q - B1; int tt = rem >> 7; src = tt / KM1;
      } else if (q < B3) {
        rem = q - B2; int tt = rem >> 7; int i = tt / KM1; int mm = tt - i * KM1;
        int s = i & 7; int bs = i & ~7;
        src = bs + mm + (mm >= s ? 1 : 0);
      } else if (q < B4) {
        rem = q - B3; int tt = rem >> 7; src = nidx[tt];
      } else {
        rem = q - B4; src = rem >> 7;
      }
      int col = rem & 127;
      v = x4[(size_t)src * (DIM / 4) + col];
    }
    o4[q] = v;
  }
}

// ---------------- launch ----------------
extern "C" void kernel_launch(void* const* d_in, const int* in_sizes, int n_in,
                              void* d_out, int out_size, void* d_ws, size_t ws_size,
                              hipStream_t stream) {
  const float* x = (const float*)d_in[0];
  float* out = (float*)d_out;

  uint8_t* ws = (uint8_t*)d_ws;
  uint32_t* mask = (uint32_t*)ws;                                          // 2 MiB
  int* nidx = (int*)(ws + (size_t)N_PTS * MASKW * 4);                      // 112 KiB
  float* sq = (float*)(ws + (size_t)N_PTS * MASKW * 4 + (size_t)NDRAW * 4);// 16 KiB

  // bf16 split planes live in d_out (184 MB) — fully overwritten by assemble later
  ushort* xs = (ushort*)d_out;

  split_kernel<<<2048, 256, 0, stream>>>(x, xs);
  sq_kernel<<<N_PTS, 64, 0, stream>>>(x, sq);
  gram_kernel<<<dim3(32, 32), 256, 0, stream>>>(xs, sq, mask);
  sample_kernel<<<NDRAW, 256, 0, stream>>>(mask, nidx);
  assemble_kernel<<<2048, 256, 0, stream>>>(x, nidx, out);
}

// Round 3
// 291.932 us; speedup vs baseline: 3.0818x; 1.9751x over previous
//
#include <hip/hip_runtime.h>
#include <stdint.h>
#include <math.h>

#define N_PTS 4096
#define DIM   512
#define KM1   7
#define NDRAW (N_PTS * KM1)     // 28672
#define MASKW (N_PTS / 32)      // 128 words per row
#define NP    ((size_t)N_PTS * DIM)

typedef __attribute__((ext_vector_type(8))) short bf16x8;
typedef __attribute__((ext_vector_type(4))) float f32x4;

// ---------------- threefry2x32, key = (0, 42), JAX partitionable bits ----------------
__device__ __forceinline__ uint32_t rotl32(uint32_t x, uint32_t r) {
  return (x << r) | (x >> (32u - r));
}

__device__ __forceinline__ uint32_t threefry_bits(uint32_t x0, uint32_t x1) {
  const uint32_t ks0 = 0u, ks1 = 42u, ks2 = (0u ^ 42u ^ 0x1BD11BDAu);
  x0 += ks0; x1 += ks1;
#define TFR(r) { x0 += x1; x1 = rotl32(x1, r); x1 ^= x0; }
  TFR(13u) TFR(15u) TFR(26u) TFR(6u)   x0 += ks1; x1 += ks2 + 1u;
  TFR(17u) TFR(29u) TFR(16u) TFR(24u)  x0 += ks2; x1 += ks0 + 2u;
  TFR(13u) TFR(15u) TFR(26u) TFR(6u)   x0 += ks0; x1 += ks1 + 3u;
  TFR(17u) TFR(29u) TFR(16u) TFR(24u)  x0 += ks1; x1 += ks2 + 4u;
  TFR(13u) TFR(15u) TFR(26u) TFR(6u)   x0 += ks2; x1 += ks0 + 5u;
#undef TFR
  return x0 ^ x1;   // partitionable 32-bit: out0 ^ out1
}

__device__ __forceinline__ ushort bf16rn(float f) {
  uint32_t u = __float_as_uint(f);
  uint32_t r = (u + 0x7FFFu + ((u >> 16) & 1u)) >> 16;
  return (ushort)r;
}

// ---------------- kernel A: split x into 3 bf16 planes (hi, mid, lo) ----------------
__global__ __launch_bounds__(256) void split_kernel(const float* __restrict__ x,
                                                    ushort* __restrict__ xs) {
  const int q = blockIdx.x * 256 + threadIdx.x;   // 0..524287, 4 floats each
  float4 v = ((const float4*)x)[q];
  float a[4] = {v.x, v.y, v.z, v.w};
  ushort4 oh, om, ol;
  ushort hh[4], mm[4], ll[4];
#pragma unroll
  for (int j = 0; j < 4; ++j) {
    float f = a[j];
    ushort hb = bf16rn(f);
    float hf = __uint_as_float(((uint32_t)hb) << 16);
    float r1 = f - hf;                 // exact in f32
    ushort mb = bf16rn(r1);
    float mf = __uint_as_float(((uint32_t)mb) << 16);
    float r2 = r1 - mf;                // exact in f32
    ushort lb = bf16rn(r2);
    hh[j] = hb; mm[j] = mb; ll[j] = lb;
  }
  oh.x = hh[0]; oh.y = hh[1]; oh.z = hh[2]; oh.w = hh[3];
  om.x = mm[0]; om.y = mm[1]; om.z = mm[2]; om.w = mm[3];
  ol.x = ll[0]; ol.y = ll[1]; ol.z = ll[2]; ol.w = ll[3];
  ((ushort4*)xs)[q]            = oh;
  ((ushort4*)(xs + NP))[q]     = om;
  ((ushort4*)(xs + 2 * NP))[q] = ol;
}

// ---------------- kernel 0: sq[i] = f32(sum_k x[i,k]^2) (f64 accumulate) ----------------
__global__ __launch_bounds__(64) void sq_kernel(const float* __restrict__ x,
                                                float* __restrict__ sq) {
  const int i = blockIdx.x;
  const int t = threadIdx.x;
  const float* row = x + (size_t)i * DIM;
  double s = 0.0;
  for (int k = t; k < DIM; k += 64) { double v = (double)row[k]; s += v * v; }
  for (int off = 32; off > 0; off >>= 1) s += __shfl_down(s, off, 64);
  if (t == 0) sq[i] = (float)s;
}

// ---------------- kernel 1: validity bitmask via split-bf16 MFMA Gram ----------------
#define BM 128
#define BK 32

__device__ __forceinline__ void gload_lds16(const ushort* g, ushort* l) {
  __builtin_amdgcn_global_load_lds((__attribute__((address_space(1))) void*)(ushort*)g,
                                   (__attribute__((address_space(3))) void*)l, 16, 0, 0);
}

__global__ __launch_bounds__(256) void gram_kernel(const ushort* __restrict__ xs,
                                                   const float* __restrict__ sq,
                                                   uint32_t* __restrict__ mask) {
  __shared__ __align__(1024) ushort As[BM * BK];   // 8 KB, linear [row][k], 64B rows
  __shared__ __align__(1024) ushort Bs[BM * BK];   // 8 KB
  __shared__ uint32_t smask[BM][4];                // 2 KB validity bits for this 128x128 tile

  const int tid = threadIdx.x;
  const int w = tid >> 6, l = tid & 63;
  const int i0 = blockIdx.y * BM, c0 = blockIdx.x * BM;
  const int wr = w >> 1, wc = w & 1;               // wave's 64x64 subtile

  ((uint32_t*)smask)[tid] = 0u;
  ((uint32_t*)smask)[tid + 256] = 0u;

  f32x4 acc[4][4] = {};

  const int d0 = (w * 2) * 1024 + l * 16;          // dest byte of lane (chunk 0)
  const int d1 = d0 + 1024;                        // chunk 1
  const int r0 = d0 >> 6, e0 = (d0 & 63) >> 1;
  const int r1 = d1 >> 6, e1 = (d1 & 63) >> 1;

  const int aoff = (wr * 64 + (l & 15)) * BK + (l >> 4) * 8;
  const int boff = (wc * 64 + (l & 15)) * BK + (l >> 4) * 8;

  const int PA[6] = {0, 0, 1, 0, 2, 1};
  const int PB[6] = {0, 1, 0, 2, 0, 1};

  for (int pair = 0; pair < 6; ++pair) {
    const ushort* pa = xs + (size_t)PA[pair] * NP + (size_t)i0 * DIM;
    const ushort* pb = xs + (size_t)PB[pair] * NP + (size_t)c0 * DIM;
    const ushort* ga0 = pa + (size_t)r0 * DIM + e0;
    const ushort* ga1 = pa + (size_t)r1 * DIM + e1;
    const ushort* gb0 = pb + (size_t)r0 * DIM + e0;
    const ushort* gb1 = pb + (size_t)r1 * DIM + e1;
#pragma unroll 4
    for (int ks = 0; ks < DIM / BK; ++ks) {
      const int k0 = ks * BK;
      __syncthreads();
      gload_lds16(ga0 + k0, &As[(w * 2 + 0) * 512]);
      gload_lds16(ga1 + k0, &As[(w * 2 + 1) * 512]);
      gload_lds16(gb0 + k0, &Bs[(w * 2 + 0) * 512]);
      gload_lds16(gb1 + k0, &Bs[(w * 2 + 1) * 512]);
      __syncthreads();
      bf16x8 af[4], bf[4];
#pragma unroll
      for (int m = 0; m < 4; ++m) af[m] = *(const bf16x8*)(&As[aoff + m * 16 * BK]);
#pragma unroll
      for (int n = 0; n < 4; ++n) bf[n] = *(const bf16x8*)(&Bs[boff + n * 16 * BK]);
#pragma unroll
      for (int m = 0; m < 4; ++m)
#pragma unroll
        for (int n = 0; n < 4; ++n)
          acc[m][n] = __builtin_amdgcn_mfma_f32_16x16x32_bf16(af[m], bf[n], acc[m][n], 0, 0, 0);
    }
  }

  __syncthreads();

#pragma unroll
  for (int m = 0; m < 4; ++m) {
    const int gi_base = i0 + wr * 64 + m * 16;
#pragma unroll
    for (int n = 0; n < 4; ++n) {
      const int gc = c0 + wc * 64 + n * 16 + (l & 15);
      const float sqc = sq[gc];
#pragma unroll
      for (int reg = 0; reg < 4; ++reg) {
        const int gi = gi_base + (l >> 4) * 4 + reg;
        float dot = acc[m][n][reg];
        float tsum = sq[gi] + sqc;
        float dist2 = tsum - 2.0f * dot;
        float d = sqrtf(dist2);
        bool v = (d < 1.4f) && ((gi >> 3) != (gc >> 3));
        unsigned long long b = __ballot(v);
        if (l < 4) {
          uint32_t chunk = (uint32_t)((b >> (16 * l)) & 0xFFFFull);
          int rowL = wr * 64 + m * 16 + 4 * l + reg;
          atomicOr(&smask[rowL][wc * 2 + (n >> 1)], chunk << (16 * (n & 1)));
        }
      }
    }
  }
  __syncthreads();
  for (int t = tid; t < 512; t += 256) {
    int row = t >> 2, wrd = t & 3;
    mask[(size_t)(i0 + row) * MASKW + (c0 >> 5) + wrd] = smask[row][wrd];
  }
}

// ---------------- kernel 2: one block per row i; compact valid list, then 7 integer-argmax draws ----------------
// argmax(gumbel+L) == argmax(bits>>9) on the valid set (monotone transform, L const per row),
// ties -> lowest c (pack key<<12 | (4095-c), take integer max).
__global__ __launch_bounds__(256) void sample_kernel(const uint32_t* __restrict__ mask,
                                                     int* __restrict__ nidx) {
  const int i = blockIdx.x;
  const int t = threadIdx.x;

  __shared__ uint32_t m[MASKW];
  __shared__ int cnt[MASKW];
  __shared__ ushort clist[N_PTS];
  __shared__ unsigned long long red[4];

  if (t < MASKW) m[t] = mask[(size_t)i * MASKW + t];
  __syncthreads();

  // inclusive scan of per-word popcounts (128 entries)
  if (t < MASKW) cnt[t] = __popc(m[t]);
  __syncthreads();
  for (int s = 1; s < MASKW; s <<= 1) {
    int v = 0;
    if (t < MASKW) { v = cnt[t]; if (t >= s) v += cnt[t - s]; }
    __syncthreads();
    if (t < MASKW) cnt[t] = v;
    __syncthreads();
  }
  // scatter valid indices compacted
  if (t < MASKW) {
    uint32_t mw = m[t];
    int off = cnt[t] - __popc(mw);
    int base_c = t << 5;
    while (mw) {
      int b = __ffs(mw) - 1;
      mw &= mw - 1;
      clist[off++] = (ushort)(base_c + b);
    }
  }
  __syncthreads();
  const int n = cnt[MASKW - 1];

  for (int j = 0; j < KM1; ++j) {
    const uint32_t base = ((uint32_t)((j << 12) + i)) << 12;   // (r<<12), r=j*4096+i
    unsigned long long best = 0ull;
    if (n > 0) {
      for (int q = t; q < n; q += 256) {
        uint32_t c = clist[q];
        uint32_t key = threefry_bits(0u, base + c) >> 9;
        unsigned long long p = ((unsigned long long)key << 12) | (unsigned long long)(4095u - c);
        if (p > best) best = p;
      }
    } else {
      // fallback: uniform over all 4096 (logits = 0)
      for (int c = t; c < N_PTS; c += 256) {
        uint32_t key = threefry_bits(0u, base + (uint32_t)c) >> 9;
        unsigned long long p = ((unsigned long long)key << 12) | (unsigned long long)(4095u - c);
        if (p > best) best = p;
      }
    }
#pragma unroll
    for (int off = 32; off > 0; off >>= 1) {
      unsigned long long o = __shfl_down(best, off, 64);
      if (o > best) best = o;
    }
    if ((t & 63) == 0) red[t >> 6] = best;
    __syncthreads();
    if (t == 0) {
      unsigned long long b = red[0];
#pragma unroll
      for (int wv = 1; wv < 4; ++wv) if (red[wv] > b) b = red[wv];
      nidx[i * KM1 + j] = 4095 - (int)(b & 0xFFFull);
    }
    __syncthreads();
  }
}

// ---------------- kernel 3: assemble (a_idx, x[a], x[p], x[n], x) ----------------
__global__ __launch_bounds__(256) void assemble_kernel(const float* __restrict__ x,
                                                       const int* __restrict__ nidx,
                                                       float* __restrict__ out) {
  const int B1 = 7168;
  const int SEC = NDRAW * (DIM / 4);
  const int B2 = B1 + SEC;
  const int B3 = B2 + SEC;
  const int B4 = B3 + SEC;
  const int TOT = B4 + N_PTS * (DIM / 4);

  const float4* x4 = (const float4*)x;
  float4* o4 = (float4*)out;

  for (int q = blockIdx.x * blockDim.x + threadIdx.x; q < TOT;
       q += gridDim.x * blockDim.x) {
    float4 v;
    if (q < B1) {
      int e = q * 4;
      v.x = (float)((e + 0) / KM1);
      v.y = (float)((e + 1) / KM1);
      v.z = (float)((e + 2) / KM1);
      v.w = (float)((e + 3) / KM1);
    } else {
      int src, rem;
      if (q < B2) {
        rem = q - B1; int tt = rem >> 7; src = tt / KM1;
      } else if (q < B3) {
        rem = q - B2; int tt = rem >> 7; int i = tt / KM1; int mm = tt - i * KM1;
        int s = i & 7; int bs = i & ~7;
        src = bs + mm + (mm >= s ? 1 : 0);
      } else if (q < B4) {
        rem = q - B3; int tt = rem >> 7; src = nidx[tt];
      } else {
        rem = q - B4; src = rem >> 7;
      }
      int col = rem & 127;
      v = x4[(size_t)src * (DIM / 4) + col];
    }
    o4[q] = v;
  }
}

// ---------------- launch ----------------
extern "C" void kernel_launch(void* const* d_in, const int* in_sizes, int n_in,
                              void* d_out, int out_size, void* d_ws, size_t ws_size,
                              hipStream_t stream) {
  const float* x = (const float*)d_in[0];
  float* out = (float*)d_out;

  uint8_t* ws = (uint8_t*)d_ws;
  uint32_t* mask = (uint32_t*)ws;                                          // 2 MiB
  int* nidx = (int*)(ws + (size_t)N_PTS * MASKW * 4);                      // 112 KiB
  float* sq = (float*)(ws + (size_t)N_PTS * MASKW * 4 + (size_t)NDRAW * 4);// 16 KiB

  // bf16 split planes live in d_out (184 MB) — fully overwritten by assemble later
  ushort* xs = (ushort*)d_out;

  split_kernel<<<2048, 256, 0, stream>>>(x, xs);
  sq_kernel<<<N_PTS, 64, 0, stream>>>(x, sq);
  gram_kernel<<<dim3(32, 32), 256, 0, stream>>>(xs, sq, mask);
  sample_kernel<<<N_PTS, 256, 0, stream>>>(mask, nidx);
  assemble_kernel<<<2048, 256, 0, stream>>>(x, nidx, out);
}

// Round 4
// 230.107 us; speedup vs baseline: 3.9098x; 1.2687x over previous
//
#include <hip/hip_runtime.h>
#include <stdint.h>
#include <math.h>

#define N_PTS 4096
#define DIM   512
#define KM1   7
#define NDRAW (N_PTS * KM1)     // 28672
#define MASKW (N_PTS / 32)      // 128 words per row
#define NP    ((size_t)N_PTS * DIM)

typedef __attribute__((ext_vector_type(8))) short bf16x8;
typedef __attribute__((ext_vector_type(4))) float f32x4;

// ---------------- threefry2x32, key = (0, 42), JAX partitionable bits ----------------
__device__ __forceinline__ uint32_t rotl32(uint32_t x, uint32_t r) {
  return (x << r) | (x >> (32u - r));
}

__device__ __forceinline__ uint32_t threefry_bits(uint32_t x0, uint32_t x1) {
  const uint32_t ks0 = 0u, ks1 = 42u, ks2 = (0u ^ 42u ^ 0x1BD11BDAu);
  x0 += ks0; x1 += ks1;
#define TFR(r) { x0 += x1; x1 = rotl32(x1, r); x1 ^= x0; }
  TFR(13u) TFR(15u) TFR(26u) TFR(6u)   x0 += ks1; x1 += ks2 + 1u;
  TFR(17u) TFR(29u) TFR(16u) TFR(24u)  x0 += ks2; x1 += ks0 + 2u;
  TFR(13u) TFR(15u) TFR(26u) TFR(6u)   x0 += ks0; x1 += ks1 + 3u;
  TFR(17u) TFR(29u) TFR(16u) TFR(24u)  x0 += ks1; x1 += ks2 + 4u;
  TFR(13u) TFR(15u) TFR(26u) TFR(6u)   x0 += ks2; x1 += ks0 + 5u;
#undef TFR
  return x0 ^ x1;   // partitionable 32-bit: out0 ^ out1
}

__device__ __forceinline__ ushort bf16rn(float f) {
  uint32_t u = __float_as_uint(f);
  uint32_t r = (u + 0x7FFFu + ((u >> 16) & 1u)) >> 16;
  return (ushort)r;
}

// ---------------- kernel A: split x into 3 bf16 planes (hi, mid, lo) ----------------
__global__ __launch_bounds__(256) void split_kernel(const float* __restrict__ x,
                                                    ushort* __restrict__ xs) {
  const int q = blockIdx.x * 256 + threadIdx.x;   // 0..524287, 4 floats each
  float4 v = ((const float4*)x)[q];
  float a[4] = {v.x, v.y, v.z, v.w};
  ushort4 oh, om, ol;
  ushort hh[4], mm[4], ll[4];
#pragma unroll
  for (int j = 0; j < 4; ++j) {
    float f = a[j];
    ushort hb = bf16rn(f);
    float hf = __uint_as_float(((uint32_t)hb) << 16);
    float r1 = f - hf;                 // exact in f32
    ushort mb = bf16rn(r1);
    float mf = __uint_as_float(((uint32_t)mb) << 16);
    float r2 = r1 - mf;                // exact in f32
    ushort lb = bf16rn(r2);
    hh[j] = hb; mm[j] = mb; ll[j] = lb;
  }
  oh.x = hh[0]; oh.y = hh[1]; oh.z = hh[2]; oh.w = hh[3];
  om.x = mm[0]; om.y = mm[1]; om.z = mm[2]; om.w = mm[3];
  ol.x = ll[0]; ol.y = ll[1]; ol.z = ll[2]; ol.w = ll[3];
  ((ushort4*)xs)[q]            = oh;
  ((ushort4*)(xs + NP))[q]     = om;
  ((ushort4*)(xs + 2 * NP))[q] = ol;
}

// ---------------- kernel 0: sq[i] = f32(sum_k x[i,k]^2) (f64 accumulate) ----------------
__global__ __launch_bounds__(64) void sq_kernel(const float* __restrict__ x,
                                                float* __restrict__ sq) {
  const int i = blockIdx.x;
  const int t = threadIdx.x;
  const float* row = x + (size_t)i * DIM;
  double s = 0.0;
  for (int k = t; k < DIM; k += 64) { double v = (double)row[k]; s += v * v; }
  for (int off = 32; off > 0; off >>= 1) s += __shfl_down(s, off, 64);
  if (t == 0) sq[i] = (float)s;
}

// ---------------- kernel 1: upper-triangle validity mask via fused 3-plane MFMA Gram ----------------
#define BM 128
#define BK 32

__device__ __forceinline__ void gload_lds16(const ushort* g, ushort* l) {
  __builtin_amdgcn_global_load_lds((__attribute__((address_space(1))) void*)(ushort*)g,
                                   (__attribute__((address_space(3))) void*)l, 16, 0, 0);
}

__global__ __launch_bounds__(256) void gram_kernel(const ushort* __restrict__ xs,
                                                   const float* __restrict__ sq,
                                                   uint32_t* __restrict__ mask) {
  __shared__ __align__(1024) ushort As[3 * BM * BK];   // 24 KB: 3 planes x 8KB
  __shared__ __align__(1024) ushort Bs[3 * BM * BK];   // 24 KB
  __shared__ uint32_t smask[BM][4];                    // 2 KB

  // triangular block map: t -> (bi, bj), 0 <= bi <= bj < 32
  {
  }
  const int tblk = blockIdx.x;
  int bi = (int)((65.0 - sqrt(4225.0 - 8.0 * (double)tblk)) * 0.5);
  while ((65 * (bi + 1) - (bi + 1) * (bi + 1)) / 2 <= tblk) ++bi;
  while ((65 * bi - bi * bi) / 2 > tblk) --bi;
  const int bj = bi + (tblk - (65 * bi - bi * bi) / 2);
  const int i0 = bi * BM, c0 = bj * BM;

  const int tid = threadIdx.x;
  const int w = tid >> 6, l = tid & 63;
  const int wr = w >> 1, wc = w & 1;               // wave's 64x64 subtile

  ((uint32_t*)smask)[tid] = 0u;
  ((uint32_t*)smask)[tid + 256] = 0u;

  f32x4 acc[4][4] = {};

  // staging geometry: per 8KB plane-tile, wave w stages bytes [w*2048, w*2048+2048)
  const int d0 = w * 2048 + l * 16;                // chunk0 byte; chunk1 = +1024
  const int r0 = d0 >> 6;                          // 64B per row
  const int e0 = (d0 & 63) >> 1;
  const ushort* asrc = xs + (size_t)(i0 + r0) * DIM + e0;
  const ushort* bsrc = xs + (size_t)(c0 + r0) * DIM + e0;

  const int aoff = (wr * 64 + (l & 15)) * BK + (l >> 4) * 8;
  const int boff = (wc * 64 + (l & 15)) * BK + (l >> 4) * 8;

#define RD(frag, buf, p) { \
  _Pragma("unroll") for (int q_ = 0; q_ < 4; ++q_) \
    frag[q_] = *(const bf16x8*)(&buf[(p) * 4096 + ((&buf[0] == &As[0]) ? aoff : boff) + q_ * 16 * BK]); }

#define MM() { \
  _Pragma("unroll") for (int m_ = 0; m_ < 4; ++m_) \
  _Pragma("unroll") for (int n_ = 0; n_ < 4; ++n_) \
    acc[m_][n_] = __builtin_amdgcn_mfma_f32_16x16x32_bf16(af[m_], bf[n_], acc[m_][n_], 0, 0, 0); }

  for (int ks = 0; ks < DIM / BK; ++ks) {
    const int k0 = ks * BK;
    __syncthreads();
#pragma unroll
    for (int p = 0; p < 3; ++p) {
      const ushort* ap = asrc + (size_t)p * NP + k0;
      const ushort* bp = bsrc + (size_t)p * NP + k0;
      gload_lds16(ap,            &As[p * 4096 + w * 1024]);
      gload_lds16(ap + 16 * DIM, &As[p * 4096 + w * 1024 + 512]);
      gload_lds16(bp,            &Bs[p * 4096 + w * 1024]);
      gload_lds16(bp + 16 * DIM, &Bs[p * 4096 + w * 1024 + 512]);
    }
    __syncthreads();
    bf16x8 af[4], bf[4];
    RD(af, As, 0); RD(bf, Bs, 0); MM();   // (h,h)
    RD(bf, Bs, 1); MM();                  // (h,m)
    RD(bf, Bs, 2); MM();                  // (h,l)
    RD(af, As, 1); RD(bf, Bs, 0); MM();   // (m,h)
    RD(bf, Bs, 1); MM();                  // (m,m)
    RD(af, As, 2); RD(bf, Bs, 0); MM();   // (l,h)
  }

  __syncthreads();

  // epilogue: dist2 -> validity bits (mirror reference f32 op order)
#pragma unroll
  for (int m = 0; m < 4; ++m) {
    const int gi_base = i0 + wr * 64 + m * 16;
#pragma unroll
    for (int n = 0; n < 4; ++n) {
      const int gc = c0 + wc * 64 + n * 16 + (l & 15);
      const float sqc = sq[gc];
#pragma unroll
      for (int reg = 0; reg < 4; ++reg) {
        const int gi = gi_base + (l >> 4) * 4 + reg;
        float dot = acc[m][n][reg];
        float tsum = sq[gi] + sqc;
        float dist2 = tsum - 2.0f * dot;
        float d = sqrtf(dist2);
        bool v = (d < 1.4f) && ((gi >> 3) != (gc >> 3));
        unsigned long long b = __ballot(v);
        if (l < 4) {
          uint32_t chunk = (uint32_t)((b >> (16 * l)) & 0xFFFFull);
          int rowL = wr * 64 + m * 16 + 4 * l + reg;
          atomicOr(&smask[rowL][wc * 2 + (n >> 1)], chunk << (16 * (n & 1)));
        }
      }
    }
  }
  __syncthreads();
  for (int t = tid; t < 512; t += 256) {
    int row = t >> 2, wrd = t & 3;
    mask[(size_t)(i0 + row) * MASKW + (c0 >> 5) + wrd] = smask[row][wrd];
  }
#undef RD
#undef MM
}

// ---------------- kernel 1b: mirror upper-triangle mask blocks to lower triangle ----------------
// 32x32 bit transpose across 32 lanes via shfl butterfly (Hacker's Delight).
__global__ __launch_bounds__(256) void mirror_kernel(uint32_t* __restrict__ mask) {
  const int t = blockIdx.x;                     // 0..495 : pairs bi < bj
  int bi = (int)((63.0 - sqrt(3969.0 - 8.0 * (double)t)) * 0.5);
  while ((63 * (bi + 1) - (bi + 1) * (bi + 1)) / 2 <= t) ++bi;
  while ((63 * bi - bi * bi) / 2 > t) --bi;
  const int bj = bi + 1 + (t - (63 * bi - bi * bi) / 2);

  const int grp = threadIdx.x >> 5;             // 8 groups of 32 lanes
  const int lane = threadIdx.x & 31;

  for (int sb = grp; sb < 16; sb += 8) {
    const int sr = sb >> 2, sc = sb & 3;
    uint32_t x = mask[(size_t)(bi * 128 + sr * 32 + lane) * MASKW + bj * 4 + sc];
    uint32_t m = 0x0000FFFFu;
#pragma unroll
    for (int s = 16; s; s >>= 1) {
      uint32_t y = (uint32_t)__shfl_xor((int)x, s, 64);
      x = (lane & s) ? (((y >> s) & m) | (x & ~m))
                     : ((x & m) | ((y & m) << s));
      m ^= (m << (s >> 1));
    }
    mask[(size_t)(bj * 128 + sc * 32 + lane) * MASKW + bi * 4 + sr] = x;
  }
}

// ---------------- kernel 2: one block per row i; compact valid list, then 7 integer-argmax draws ----------------
__global__ __launch_bounds__(256) void sample_kernel(const uint32_t* __restrict__ mask,
                                                     int* __restrict__ nidx) {
  const int i = blockIdx.x;
  const int t = threadIdx.x;

  __shared__ uint32_t m[MASKW];
  __shared__ int cnt[MASKW];
  __shared__ ushort clist[N_PTS];
  __shared__ unsigned long long red[4];

  if (t < MASKW) m[t] = mask[(size_t)i * MASKW + t];
  __syncthreads();

  if (t < MASKW) cnt[t] = __popc(m[t]);
  __syncthreads();
  for (int s = 1; s < MASKW; s <<= 1) {
    int v = 0;
    if (t < MASKW) { v = cnt[t]; if (t >= s) v += cnt[t - s]; }
    __syncthreads();
    if (t < MASKW) cnt[t] = v;
    __syncthreads();
  }
  if (t < MASKW) {
    uint32_t mw = m[t];
    int off = cnt[t] - __popc(mw);
    int base_c = t << 5;
    while (mw) {
      int b = __ffs(mw) - 1;
      mw &= mw - 1;
      clist[off++] = (ushort)(base_c + b);
    }
  }
  __syncthreads();
  const int n = cnt[MASKW - 1];

  for (int j = 0; j < KM1; ++j) {
    const uint32_t base = ((uint32_t)((j << 12) + i)) << 12;   // (r<<12), r=j*4096+i
    unsigned long long best = 0ull;
    if (n > 0) {
      for (int q = t; q < n; q += 256) {
        uint32_t c = clist[q];
        uint32_t key = threefry_bits(0u, base + c) >> 9;
        unsigned long long p = ((unsigned long long)key << 12) | (unsigned long long)(4095u - c);
        if (p > best) best = p;
      }
    } else {
      for (int c = t; c < N_PTS; c += 256) {
        uint32_t key = threefry_bits(0u, base + (uint32_t)c) >> 9;
        unsigned long long p = ((unsigned long long)key << 12) | (unsigned long long)(4095u - c);
        if (p > best) best = p;
      }
    }
#pragma unroll
    for (int off = 32; off > 0; off >>= 1) {
      unsigned long long o = __shfl_down(best, off, 64);
      if (o > best) best = o;
    }
    if ((t & 63) == 0) red[t >> 6] = best;
    __syncthreads();
    if (t == 0) {
      unsigned long long b = red[0];
#pragma unroll
      for (int wv = 1; wv < 4; ++wv) if (red[wv] > b) b = red[wv];
      nidx[i * KM1 + j] = 4095 - (int)(b & 0xFFFull);
    }
    __syncthreads();
  }
}

// ---------------- kernel 3: assemble (a_idx, x[a], x[p], x[n], x) ----------------
__global__ __launch_bounds__(256) void assemble_kernel(const float* __restrict__ x,
                                                       const int* __restrict__ nidx,
                                                       float* __restrict__ out) {
  const int B1 = 7168;
  const int SEC = NDRAW * (DIM / 4);
  const int B2 = B1 + SEC;
  const int B3 = B2 + SEC;
  const int B4 = B3 + SEC;
  const int TOT = B4 + N_PTS * (DIM / 4);

  const float4* x4 = (const float4*)x;
  float4* o4 = (float4*)out;

  for (int q = blockIdx.x * blockDim.x + threadIdx.x; q < TOT;
       q += gridDim.x * blockDim.x) {
    float4 v;
    if (q < B1) {
      int e = q * 4;
      v.x = (float)((e + 0) / KM1);
      v.y = (float)((e + 1) / KM1);
      v.z = (float)((e + 2) / KM1);
      v.w = (float)((e + 3) / KM1);
    } else {
      int src, rem;
      if (q < B2) {
        rem = q - B1; int tt = rem >> 7; src = tt / KM1;
      } else if (q < B3) {
        rem = q - B2; int tt = rem >> 7; int i = tt / KM1; int mm = tt - i * KM1;
        int s = i & 7; int bs = i & ~7;
        src = bs + mm + (mm >= s ? 1 : 0);
      } else if (q < B4) {
        rem = q - B3; int tt = rem >> 7; src = nidx[tt];
      } else {
        rem = q - B4; src = rem >> 7;
      }
      int col = rem & 127;
      v = x4[(size_t)src * (DIM / 4) + col];
    }
    o4[q] = v;
  }
}

// ---------------- launch ----------------
extern "C" void kernel_launch(void* const* d_in, const int* in_sizes, int n_in,
                              void* d_out, int out_size, void* d_ws, size_t ws_size,
                              hipStream_t stream) {
  const float* x = (const float*)d_in[0];
  float* out = (float*)d_out;

  uint8_t* ws = (uint8_t*)d_ws;
  uint32_t* mask = (uint32_t*)ws;                                          // 2 MiB
  int* nidx = (int*)(ws + (size_t)N_PTS * MASKW * 4);                      // 112 KiB
  float* sq = (float*)(ws + (size_t)N_PTS * MASKW * 4 + (size_t)NDRAW * 4);// 16 KiB

  // bf16 split planes live in d_out (184 MB) — fully overwritten by assemble later
  ushort* xs = (ushort*)d_out;

  split_kernel<<<2048, 256, 0, stream>>>(x, xs);
  sq_kernel<<<N_PTS, 64, 0, stream>>>(x, sq);
  gram_kernel<<<528, 256, 0, stream>>>(xs, sq, mask);
  mirror_kernel<<<496, 256, 0, stream>>>(mask);
  sample_kernel<<<N_PTS, 256, 0, stream>>>(mask, nidx);
  assemble_kernel<<<2048, 256, 0, stream>>>(x, nidx, out);
}